// Round 17
// baseline (1408.823 us; speedup 1.0000x reference)
//
#include <hip/hip_runtime.h>
#include <math.h>

#define NS 512
#define NE 2048
#define NB 64
#define NT 512
#define SENT 0x7FC0DEADu  // NaN payload; real values are always finite

// out[c][r] = in[r][c]; rows, cols multiples of 32
__global__ __launch_bounds__(256) void transpose_k(const float* __restrict__ in,
                                                   float* __restrict__ out,
                                                   int rows, int cols) {
  __shared__ float tile[32][33];
  int c0 = blockIdx.x * 32;
  int r0 = blockIdx.y * 32;
  int tx = threadIdx.x;  // 0..31
  int ty = threadIdx.y;  // 0..7
#pragma unroll
  for (int k = 0; k < 32; k += 8) {
    tile[ty + k][tx] = in[(size_t)(r0 + ty + k) * cols + (c0 + tx)];
  }
  __syncthreads();
#pragma unroll
  for (int k = 0; k < 32; k += 8) {
    out[(size_t)(c0 + ty + k) * rows + (r0 + tx)] = tile[tx][ty + k];
  }
}

// Fill the whole vpre buffer with the sentinel each call (slots write-once per
// call; harness does not re-poison between replays). Row t=0 is overwritten by
// fwd's init (plain stores) before anyone reads it.
__global__ __launch_bounds__(256) void fill_sentinel(float* __restrict__ vpre) {
  uint4 s = make_uint4(SENT, SENT, SENT, SENT);
  uint4* p = reinterpret_cast<uint4*>(vpre);
  const size_t n4 = (size_t)NB * NT * NS / 4;
  for (size_t i = (size_t)blockIdx.x * blockDim.x + threadIdx.x; i < n4;
       i += (size_t)gridDim.x * blockDim.x)
    p[i] = s;
}

// Forward, dataflow column-slice, MAX-ONLY (R16 structure minus the argmax
// that made R16 VALU-bound: 82.5% busy). Grid 512 = 64 groups x 8 members.
// Member m owns columns [64m,64m+64); wave oct owns i-block p=(m+oct)&7
// entirely and gathers exactly the slice it consumes (sentinel retry, no
// cross-wave gather barrier; single __syncthreads per iteration; parity
// partials). Exchange value = PRE-EMISSION max mv (vpre[g][t][j], batch-major
// for bt locality); consumers add the emission row after gathering (prefetched,
// off E's chain). bt recomputes fl(fl(vpre+e)+T) — bit-identical expressions —
// so no argmax/backpointers are needed anywhere in fwd.
__global__ __launch_bounds__(512) void viterbi_fwd(
    const int* __restrict__ obs,     // [NB][NT]
    const float* __restrict__ start, // [NS]
    const float* __restrict__ trans, // [NS][NS]
    const float* __restrict__ emT,   // [NE][NS]
    float* __restrict__ vpre)        // [NB][NT][NS] exchange + bt input
{
  const int g = blockIdx.x & 63;
  const int m = blockIdx.x >> 6;       // member 0..7
  const int tid = threadIdx.x;
  const int jl = tid & 63;
  const int oct = tid >> 6;            // wave 0..7
  const int j = m * 64 + jl;           // my output column
  const int p = (m + oct) & 7;         // i-block this wave covers
  const int i0 = p * 64;

  __shared__ __align__(16) float vf[NS];
  __shared__ float part_v[2][8][64];
  __shared__ int obs_s[NT];

  obs_s[tid] = obs[g * NT + tid];
  // t = 0: vf = v0 (post-emission) for all blocks; vpre[g][0] = start row
  // (bt's t=1 candidates recompute fl(start+e0) — identical to this init).
  {
    int o0 = obs[g * NT];
    vf[tid] = start[tid] + emT[(size_t)o0 * NS + tid];
    if (m == 0) vpre[(size_t)g * NT * NS + tid] = start[tid];
  }
  __syncthreads();

  for (int t = 1; t < NT; ++t) {
    const int par = t & 1;
    float e_own = 0.f;
    if (oct == 0) e_own = emT[(size_t)obs_s[t] * NS + j];  // for E(t)

    // ---- per-wave gather of exactly my slice (sentinel retry) ----
    if (t >= 2 && oct != 0) {
      float e_gat = emT[(size_t)obs_s[t - 1] * NS + i0 + jl];  // in flight early
      const float* ap = vpre + ((size_t)g * NT + (t - 1)) * NS + i0 + jl;
      float ga = __hip_atomic_load(ap, __ATOMIC_RELAXED, __HIP_MEMORY_SCOPE_AGENT);
      while (__any(__float_as_uint(ga) == SENT)) {
        __builtin_amdgcn_s_sleep(1);
        ga = __hip_atomic_load(ap, __ATOMIC_RELAXED, __HIP_MEMORY_SCOPE_AGENT);
      }
      vf[i0 + jl] = ga + e_gat;  // consumed only by this wave
    }
    // wave0's block (p==m) was written by its own E(t-1): same-wave order.

    // ---- compute block p for column j: max only (1.5 VALU/score) ----
    float acc = -INFINITY;
    {
      const float* tp = trans + (size_t)i0 * NS + j;
      const float4* va = reinterpret_cast<const float4*>(vf + i0);
#pragma unroll
      for (int c = 0; c < 16; ++c) {
        float4 x = va[c];
        float s0 = x.x + tp[(size_t)(4 * c + 0) * NS];
        float s1 = x.y + tp[(size_t)(4 * c + 1) * NS];
        float s2 = x.z + tp[(size_t)(4 * c + 2) * NS];
        float s3 = x.w + tp[(size_t)(4 * c + 3) * NS];
        acc = fmaxf(acc, fmaxf(fmaxf(s0, s1), fmaxf(s2, s3)));
      }
    }
    if (oct != 0) part_v[par][oct][jl] = acc;
    __syncthreads();  // the ONE barrier: parts(t) ready for E(t)

    // ---- E: wave0 merges 8 partials (max), publishes vpre[t] ----
    if (oct == 0) {
      float mv = acc;  // own block partial
#pragma unroll
      for (int o = 1; o < 8; ++o) mv = fmaxf(mv, part_v[par][o][jl]);
      vf[j] = mv + e_own;  // own block for next iter's wave0 compute
      __hip_atomic_store(vpre + ((size_t)g * NT + t) * NS + j, mv,
                         __ATOMIC_RELAXED, __HIP_MEMORY_SCOPE_AGENT);
    }
  }
}

// Backtrace by exact value-match: s_{t-1} = first i with
//   fl(fl(vpre[t-1][i] + e[t-1][i]) + transT[s_t][i]) == vpre[t][s_t].
// All expressions bit-identical to fwd's compute -> match guaranteed & exact
// first-wins. Chain per step: 2 parallel dependent L2-hit loads + 8 add/cmp +
// ballot + ffs + 1 shfl. transT warmed once; vpre warmed in 128-row chunks
// (256KB: 8 blocks/XCD x chunk + transT 1MB fits 4MB L2).
__global__ __launch_bounds__(64) void viterbi_bt(
    const int* __restrict__ obs,      // [NB][NT]
    const float* __restrict__ emT,    // [NE][NS]
    const float* __restrict__ transT, // [NS][NS], transT[j][i] = trans[i][j]
    const float* __restrict__ vpre,   // [NB][NT][NS]
    int* __restrict__ path)           // [NB][NT] int32
{
  const int b = blockIdx.x;
  const int lane = threadIdx.x;
  __shared__ int obs_s[NT];
  for (int i = lane; i < NT; i += 64) obs_s[i] = obs[b * NT + i];

  // warm transT (1MB) into this XCD's L2 (keep-alive asm, rule #17)
  {
    const uint4* w = reinterpret_cast<const uint4*>(transT);
#pragma unroll 4
    for (int i = lane; i < NS * NS / 4; i += 64) {
      uint4 x = w[i];
      asm volatile("" ::"v"(x.x), "v"(x.y), "v"(x.z), "v"(x.w));
    }
  }
  // warm vpre rows [384..511] (first chunk)
  {
    const uint4* w = reinterpret_cast<const uint4*>(vpre + ((size_t)b * NT + 384) * NS);
#pragma unroll 4
    for (int i = lane; i < 128 * NS / 4; i += 64) {
      uint4 x = w[i];
      asm volatile("" ::"v"(x.x), "v"(x.y), "v"(x.z), "v"(x.w));
    }
  }
  __syncthreads();

  // final argmax over v[NT-1] = vpre[NT-1] + e[NT-1] (first-wins)
  int state;
  {
    const float4* vr = reinterpret_cast<const float4*>(vpre + ((size_t)b * NT + (NT - 1)) * NS);
    const float4* er = reinterpret_cast<const float4*>(emT + (size_t)obs_s[NT - 1] * NS);
    float4 a0 = vr[2 * lane], a1 = vr[2 * lane + 1];
    float4 e0 = er[2 * lane], e1 = er[2 * lane + 1];
    float s0 = a0.x + e0.x, s1 = a0.y + e0.y, s2 = a0.z + e0.z, s3 = a0.w + e0.w;
    float s4 = a1.x + e1.x, s5 = a1.y + e1.y, s6 = a1.z + e1.z, s7 = a1.w + e1.w;
    float lm = fmaxf(fmaxf(fmaxf(s0, s1), fmaxf(s2, s3)),
                     fmaxf(fmaxf(s4, s5), fmaxf(s6, s7)));
    float M = lm;
#pragma unroll
    for (int off = 1; off < 64; off <<= 1) M = fmaxf(M, __shfl_xor(M, off));
    int k = 7;
    if (s6 == M) k = 6;
    if (s5 == M) k = 5;
    if (s4 == M) k = 4;
    if (s3 == M) k = 3;
    if (s2 == M) k = 2;
    if (s1 == M) k = 1;
    if (s0 == M) k = 0;
    unsigned long long bal = __ballot(lm == M);
    state = __shfl(8 * lane + k, __ffsll(bal) - 1);
  }
  if (lane == 0) path[b * NT + (NT - 1)] = state;

  // prefetch rows for t-1 = NT-2
  float4 vp0, vp1, ep0, ep1;
  {
    const float4* vp = reinterpret_cast<const float4*>(vpre + ((size_t)b * NT + (NT - 2)) * NS);
    vp0 = vp[2 * lane];
    vp1 = vp[2 * lane + 1];
    const float4* ep = reinterpret_cast<const float4*>(emT + (size_t)obs_s[NT - 2] * NS);
    ep0 = ep[2 * lane];
    ep1 = ep[2 * lane + 1];
  }

  for (int t = NT - 1; t >= 1; --t) {
    if ((t & 127) == 0 && t >= 128) {  // warm next vpre chunk [t-128, t-1]
      const uint4* w = reinterpret_cast<const uint4*>(vpre + ((size_t)b * NT + (t - 128)) * NS);
#pragma unroll 4
      for (int i = lane; i < 128 * NS / 4; i += 64) {
        uint4 x = w[i];
        asm volatile("" ::"v"(x.x), "v"(x.y), "v"(x.z), "v"(x.w));
      }
    }
    // candidate base values v[t-1][i] (independent of state)
    float c0 = vp0.x + ep0.x, c1 = vp0.y + ep0.y, c2 = vp0.z + ep0.z, c3 = vp0.w + ep0.w;
    float c4 = vp1.x + ep1.x, c5 = vp1.y + ep1.y, c6 = vp1.z + ep1.z, c7 = vp1.w + ep1.w;
    // issue next prefetch (t-2)
    float4 nv0, nv1, ne0, ne1;
    if (t >= 2) {
      const float4* vp = reinterpret_cast<const float4*>(vpre + ((size_t)b * NT + (t - 2)) * NS);
      nv0 = vp[2 * lane];
      nv1 = vp[2 * lane + 1];
      const float4* ep = reinterpret_cast<const float4*>(emT + (size_t)obs_s[t - 2] * NS);
      ne0 = ep[2 * lane];
      ne1 = ep[2 * lane + 1];
    }
    // dependent loads (parallel): m* and transT row
    float mstar = vpre[((size_t)b * NT + t) * NS + state];
    const float4* tr = reinterpret_cast<const float4*>(transT + (size_t)state * NS);
    float4 t0 = tr[2 * lane], t1 = tr[2 * lane + 1];

    bool m0 = (c0 + t0.x) == mstar, m1 = (c1 + t0.y) == mstar;
    bool m2 = (c2 + t0.z) == mstar, m3 = (c3 + t0.w) == mstar;
    bool m4 = (c4 + t1.x) == mstar, m5 = (c5 + t1.y) == mstar;
    bool m6 = (c6 + t1.z) == mstar, m7 = (c7 + t1.w) == mstar;
    int k = 7;
    if (m6) k = 6;
    if (m5) k = 5;
    if (m4) k = 4;
    if (m3) k = 3;
    if (m2) k = 2;
    if (m1) k = 1;
    if (m0) k = 0;
    unsigned long long bal = __ballot(m0 | m1 | m2 | m3 | m4 | m5 | m6 | m7);
    state = __shfl(8 * lane + k, __ffsll(bal) - 1);

    if (lane == 0) path[b * NT + (t - 1)] = state;
    vp0 = nv0; vp1 = nv1; ep0 = ne0; ep1 = ne1;
  }
}

extern "C" void kernel_launch(void* const* d_in, const int* in_sizes, int n_in,
                              void* d_out, int out_size, void* d_ws, size_t ws_size,
                              hipStream_t stream) {
  const int* obs = (const int*)d_in[0];       // [64][512]
  const float* start = (const float*)d_in[1]; // [512]
  const float* trans = (const float*)d_in[2]; // [512][512]
  const float* emis = (const float*)d_in[3];  // [512][2048]
  int* path = (int*)d_out;                    // [64][512] int32

  char* ws = (char*)d_ws;
  float* emT = (float*)ws;                           // [2048][512] = 4 MB
  float* transT = (float*)(ws + (4ull << 20));       // [512][512]  = 1 MB
  float* vpre = (float*)(ws + (5ull << 20));         // [64][512][512] = 64 MB

  fill_sentinel<<<1024, 256, 0, stream>>>(vpre);

  dim3 tb(32, 8);
  transpose_k<<<dim3(NE / 32, NS / 32), tb, 0, stream>>>(emis, emT, NS, NE);
  transpose_k<<<dim3(NS / 32, NS / 32), tb, 0, stream>>>(trans, transT, NS, NS);
  viterbi_fwd<<<512, 512, 0, stream>>>(obs, start, trans, emT, vpre);
  viterbi_bt<<<NB, 64, 0, stream>>>(obs, emT, transT, vpre, path);
}

// Round 18
// 926.301 us; speedup vs baseline: 1.5209x; 1.5209x over previous
//
#include <hip/hip_runtime.h>
#include <math.h>

#define NS 512
#define NE 2048
#define NB 64
#define NT 512
#define SENT 0x7FC0DEADu  // NaN payload; real values are always finite

// out[c][r] = in[r][c]; rows, cols multiples of 32
__global__ __launch_bounds__(256) void transpose_k(const float* __restrict__ in,
                                                   float* __restrict__ out,
                                                   int rows, int cols) {
  __shared__ float tile[32][33];
  int c0 = blockIdx.x * 32;
  int r0 = blockIdx.y * 32;
  int tx = threadIdx.x;  // 0..31
  int ty = threadIdx.y;  // 0..7
#pragma unroll
  for (int k = 0; k < 32; k += 8) {
    tile[ty + k][tx] = in[(size_t)(r0 + ty + k) * cols + (c0 + tx)];
  }
  __syncthreads();
#pragma unroll
  for (int k = 0; k < 32; k += 8) {
    out[(size_t)(c0 + ty + k) * rows + (r0 + tx)] = tile[tx][ty + k];
  }
}

// Fill the whole vpre buffer with the sentinel each call (slots write-once per
// call; harness does not re-poison between replays).
__global__ __launch_bounds__(256) void fill_sentinel(float* __restrict__ vpre) {
  uint4 s = make_uint4(SENT, SENT, SENT, SENT);
  uint4* p = reinterpret_cast<uint4*>(vpre);
  const size_t n4 = (size_t)NB * NT * NS / 4;
  for (size_t i = (size_t)blockIdx.x * blockDim.x + threadIdx.x; i < n4;
       i += (size_t)gridDim.x * blockDim.x)
    p[i] = s;
}

// Forward (unchanged from R17, hit its prediction ~620us): dataflow
// column-slice, max-only. Grid 512 = 64 groups x 8 members. Member m owns
// columns [64m,64m+64); wave oct owns i-block p=(m+oct)&7 entirely and
// gathers exactly the slice it consumes (sentinel retry, no cross-wave gather
// barrier; single __syncthreads per iteration; parity partials). Exchange
// value = PRE-EMISSION max (vpre[g][t][j]); consumers add the emission row
// after gathering. bt recomputes fl(fl(vpre+e)+T) — bit-identical — so no
// argmax/backpointers exist anywhere in fwd (R16: in-loop argmax = 82% VALU).
__global__ __launch_bounds__(512) void viterbi_fwd(
    const int* __restrict__ obs,     // [NB][NT]
    const float* __restrict__ start, // [NS]
    const float* __restrict__ trans, // [NS][NS]
    const float* __restrict__ emT,   // [NE][NS]
    float* __restrict__ vpre)        // [NB][NT][NS] exchange + bt input
{
  const int g = blockIdx.x & 63;
  const int m = blockIdx.x >> 6;       // member 0..7
  const int tid = threadIdx.x;
  const int jl = tid & 63;
  const int oct = tid >> 6;            // wave 0..7
  const int j = m * 64 + jl;           // my output column
  const int p = (m + oct) & 7;         // i-block this wave covers
  const int i0 = p * 64;

  __shared__ __align__(16) float vf[NS];
  __shared__ float part_v[2][8][64];
  __shared__ int obs_s[NT];

  obs_s[tid] = obs[g * NT + tid];
  {
    int o0 = obs[g * NT];
    vf[tid] = start[tid] + emT[(size_t)o0 * NS + tid];
    if (m == 0) vpre[(size_t)g * NT * NS + tid] = start[tid];
  }
  __syncthreads();

  for (int t = 1; t < NT; ++t) {
    const int par = t & 1;
    float e_own = 0.f;
    if (oct == 0) e_own = emT[(size_t)obs_s[t] * NS + j];  // for E(t)

    // ---- per-wave gather of exactly my slice (sentinel retry) ----
    if (t >= 2 && oct != 0) {
      float e_gat = emT[(size_t)obs_s[t - 1] * NS + i0 + jl];  // in flight early
      const float* ap = vpre + ((size_t)g * NT + (t - 1)) * NS + i0 + jl;
      float ga = __hip_atomic_load(ap, __ATOMIC_RELAXED, __HIP_MEMORY_SCOPE_AGENT);
      while (__any(__float_as_uint(ga) == SENT)) {
        __builtin_amdgcn_s_sleep(1);
        ga = __hip_atomic_load(ap, __ATOMIC_RELAXED, __HIP_MEMORY_SCOPE_AGENT);
      }
      vf[i0 + jl] = ga + e_gat;  // consumed only by this wave
    }

    // ---- compute block p for column j: max only (1.5 VALU/score) ----
    float acc = -INFINITY;
    {
      const float* tp = trans + (size_t)i0 * NS + j;
      const float4* va = reinterpret_cast<const float4*>(vf + i0);
#pragma unroll
      for (int c = 0; c < 16; ++c) {
        float4 x = va[c];
        float s0 = x.x + tp[(size_t)(4 * c + 0) * NS];
        float s1 = x.y + tp[(size_t)(4 * c + 1) * NS];
        float s2 = x.z + tp[(size_t)(4 * c + 2) * NS];
        float s3 = x.w + tp[(size_t)(4 * c + 3) * NS];
        acc = fmaxf(acc, fmaxf(fmaxf(s0, s1), fmaxf(s2, s3)));
      }
    }
    if (oct != 0) part_v[par][oct][jl] = acc;
    __syncthreads();  // the ONE barrier: parts(t) ready for E(t)

    // ---- E: wave0 merges 8 partials (max), publishes vpre[t] ----
    if (oct == 0) {
      float mv = acc;
#pragma unroll
      for (int o = 1; o < 8; ++o) mv = fmaxf(mv, part_v[par][o][jl]);
      vf[j] = mv + e_own;
      __hip_atomic_store(vpre + ((size_t)g * NT + t) * NS + j, mv,
                         __ATOMIC_RELAXED, __HIP_MEMORY_SCOPE_AGENT);
    }
  }
}

// Backtrace, producer/consumer: 512 threads. Wave 0 chases; waves 1-7 stage
// vpre 32-row chunks (64KB) into double-buffered LDS one segment ahead and
// warm a transT slice into L2 once (slice-partitioned across blocks so each
// XCD gets full coverage). Segment k = steps [32k+1 .. 32k+32] reads ONLY
// chunk k from LDS; mstar (= vpre[t][s_t]) is carried in a register, updated
// by one broadcast ds_read per step — so the only state-dependent global load
// is the transT row (L2-hit ~225cy). Exact value-match (bit-identical to fwd)
// gives first-wins argmax: ballot + ffs + one shfl per step.
__global__ __launch_bounds__(512) void viterbi_bt(
    const int* __restrict__ obs,      // [NB][NT]
    const float* __restrict__ emT,    // [NE][NS]
    const float* __restrict__ transT, // [NS][NS], transT[j][i] = trans[i][j]
    const float* __restrict__ vpre,   // [NB][NT][NS]
    int* __restrict__ path)           // [NB][NT] int32
{
  const int b = blockIdx.x;
  const int tid = threadIdx.x;
  const int lane = tid & 63;
  const int oct = tid >> 6;

  __shared__ float vstage[2][32][NS];  // 128 KB, chunk k lives in buf k&1
  __shared__ int obs_s[NT];

  obs_s[tid] = obs[b * NT + tid];

  // stage chunk 15 (rows 480..511) into buf 1 — all 512 threads
  {
    const float4* src = reinterpret_cast<const float4*>(vpre + ((size_t)b * NT + 480) * NS);
    float4* dst = reinterpret_cast<float4*>(&vstage[1][0][0]);
    for (int i = tid; i < 32 * NS / 4; i += 512) dst[i] = src[i];
  }
  __syncthreads();

  int state = 0;
  float mstar = 0.f;
  float4 ep0, ep1;  // emission row t-1, wave0 only

  if (oct == 0) {
    // final argmax over v[511] = vstage[1][31] + e[511] (first-wins)
    const float4* vr = reinterpret_cast<const float4*>(&vstage[1][31][0]);
    const float4* er = reinterpret_cast<const float4*>(emT + (size_t)obs_s[NT - 1] * NS);
    float4 a0 = vr[2 * lane], a1 = vr[2 * lane + 1];
    float4 e0 = er[2 * lane], e1 = er[2 * lane + 1];
    float s0 = a0.x + e0.x, s1 = a0.y + e0.y, s2 = a0.z + e0.z, s3 = a0.w + e0.w;
    float s4 = a1.x + e1.x, s5 = a1.y + e1.y, s6 = a1.z + e1.z, s7 = a1.w + e1.w;
    float lm = fmaxf(fmaxf(fmaxf(s0, s1), fmaxf(s2, s3)),
                     fmaxf(fmaxf(s4, s5), fmaxf(s6, s7)));
    float M = lm;
#pragma unroll
    for (int off = 1; off < 64; off <<= 1) M = fmaxf(M, __shfl_xor(M, off));
    int k = 7;
    if (s6 == M) k = 6;
    if (s5 == M) k = 5;
    if (s4 == M) k = 4;
    if (s3 == M) k = 3;
    if (s2 == M) k = 2;
    if (s1 == M) k = 1;
    if (s0 == M) k = 0;
    unsigned long long bal = __ballot(lm == M);
    state = __shfl(8 * lane + k, __ffsll(bal) - 1);
    mstar = vstage[1][31][state];  // broadcast ds_read
    if (lane == 0) path[b * NT + (NT - 1)] = state;
    const float4* ep = reinterpret_cast<const float4*>(emT + (size_t)obs_s[NT - 2] * NS);
    ep0 = ep[2 * lane];
    ep1 = ep[2 * lane + 1];
  }

  for (int k = 15; k >= 0; --k) {
    if (oct != 0) {
      if (k > 0) {  // stage chunk k-1 into buf (k-1)&1
        const float4* src =
            reinterpret_cast<const float4*>(vpre + ((size_t)b * NT + (k - 1) * 32) * NS);
        float4* dst = reinterpret_cast<float4*>(&vstage[(k - 1) & 1][0][0]);
        for (int i = tid - 64; i < 32 * NS / 4; i += 448) dst[i] = src[i];
      }
      if (k == 15) {  // warm my transT slice (1/8 of 1MB) into this XCD's L2
        const uint4* w = reinterpret_cast<const uint4*>(transT) +
                         (size_t)((b >> 3) & 7) * (NS * NS / 4 / 8);
        for (int i = tid - 64; i < NS * NS / 4 / 8; i += 448) {
          uint4 x = w[i];
          asm volatile("" ::"v"(x.x), "v"(x.y), "v"(x.z), "v"(x.w));
        }
      }
    } else {
      const int hi = (k == 15) ? (NT - 1) : (32 * k + 32);
      const int lo = 32 * k + 1;
      const int buf = k & 1;
      for (int t = hi; t >= lo; --t) {
        // candidates row t-1 (LDS, state-independent) + emission regs
        const float4* cv = reinterpret_cast<const float4*>(&vstage[buf][(t - 1) & 31][0]);
        float4 vp0 = cv[2 * lane], vp1 = cv[2 * lane + 1];
        // dependent load: transT row for current state (L2-warm)
        const float4* tr = reinterpret_cast<const float4*>(transT + (size_t)state * NS);
        float4 t0 = tr[2 * lane], t1 = tr[2 * lane + 1];
        // prefetch next emission row (t-2), independent of state
        float4 ne0 = ep0, ne1 = ep1;
        if (t >= 2) {
          const float4* ep = reinterpret_cast<const float4*>(emT + (size_t)obs_s[t - 2] * NS);
          ne0 = ep[2 * lane];
          ne1 = ep[2 * lane + 1];
        }
        float c0 = vp0.x + ep0.x, c1 = vp0.y + ep0.y, c2 = vp0.z + ep0.z, c3 = vp0.w + ep0.w;
        float c4 = vp1.x + ep1.x, c5 = vp1.y + ep1.y, c6 = vp1.z + ep1.z, c7 = vp1.w + ep1.w;
        bool m0 = (c0 + t0.x) == mstar, m1 = (c1 + t0.y) == mstar;
        bool m2 = (c2 + t0.z) == mstar, m3 = (c3 + t0.w) == mstar;
        bool m4 = (c4 + t1.x) == mstar, m5 = (c5 + t1.y) == mstar;
        bool m6 = (c6 + t1.z) == mstar, m7 = (c7 + t1.w) == mstar;
        int kk = 7;
        if (m6) kk = 6;
        if (m5) kk = 5;
        if (m4) kk = 4;
        if (m3) kk = 3;
        if (m2) kk = 2;
        if (m1) kk = 1;
        if (m0) kk = 0;
        unsigned long long bal = __ballot(m0 | m1 | m2 | m3 | m4 | m5 | m6 | m7);
        state = __shfl(8 * lane + kk, __ffsll(bal) - 1);
        mstar = vstage[buf][(t - 1) & 31][state];  // broadcast ds_read, row t-1 in chunk k
        if (lane == 0) path[b * NT + t - 1] = state;
        ep0 = ne0;
        ep1 = ne1;
      }
    }
    __syncthreads();  // chunk k-1 staged; wave0 done with chunk k
  }
}

extern "C" void kernel_launch(void* const* d_in, const int* in_sizes, int n_in,
                              void* d_out, int out_size, void* d_ws, size_t ws_size,
                              hipStream_t stream) {
  const int* obs = (const int*)d_in[0];       // [64][512]
  const float* start = (const float*)d_in[1]; // [512]
  const float* trans = (const float*)d_in[2]; // [512][512]
  const float* emis = (const float*)d_in[3];  // [512][2048]
  int* path = (int*)d_out;                    // [64][512] int32

  char* ws = (char*)d_ws;
  float* emT = (float*)ws;                           // [2048][512] = 4 MB
  float* transT = (float*)(ws + (4ull << 20));       // [512][512]  = 1 MB
  float* vpre = (float*)(ws + (5ull << 20));         // [64][512][512] = 64 MB

  fill_sentinel<<<1024, 256, 0, stream>>>(vpre);

  dim3 tb(32, 8);
  transpose_k<<<dim3(NE / 32, NS / 32), tb, 0, stream>>>(emis, emT, NS, NE);
  transpose_k<<<dim3(NS / 32, NS / 32), tb, 0, stream>>>(trans, transT, NS, NS);
  viterbi_fwd<<<512, 512, 0, stream>>>(obs, start, trans, emT, vpre);
  viterbi_bt<<<NB, 512, 0, stream>>>(obs, emT, transT, vpre, path);
}